// Round 6
// baseline (3334.212 us; speedup 1.0000x reference)
//
#include <hip/hip_runtime.h>

// ComplexModel: 2-layer LSTM (B=64,T=256,D=512,H=1024) + FC head, MI355X gfx950.
// R13 = R12 resubmission (previous round died in infra before running; audit
// found no kernel-side hang path). Design:
//  - R11 lesson: halving LLC broadcast (16->8MB/step) didn't help -> the wall is
//    the agent-load bypass of L2 (16 blocks/XCD each re-pull the same bytes from
//    LLC) stacked on the phased chain.
//  - h slots are WRITE-ONCE addresses => a plain cached load returns either the
//    final value or the 0x7FFF sentinel, never stale real data. So:
//    consumer initial loads = PLAIN (L2-cacheable, dedup across the XCD);
//    sentinel-verify retries = agent bypass loads (truth, as R9/R11).
//  - producer publishes h (agent u64), then per-wave s_waitcnt vmcnt(0) +
//    s_barrier, THEN tid0 flag. Flag-visible => h at LLC => plain loads are
//    clean in steady state (pollution still handled by the retry path).
//    This end-of-step barrier also fixes R11's latent intra-block race
//    (next-step As staging vs lagging wave's p=3 MFMA reads).
//  - per-wave flag gating: each wave needs exactly 8 producers (2 per quarter);
//    poll those 8 flags, not all 64 -> tail-of-8.
//  Math bit-identical to R11 (same fragments, same 2-chain even/odd order).

#define NT 512

typedef _Float16 f16x8 __attribute__((ext_vector_type(8)));
typedef _Float16 f16x4 __attribute__((ext_vector_type(4)));
typedef float f32x4 __attribute__((ext_vector_type(4)));
typedef unsigned long long u64;

__device__ __forceinline__ float sigm(float x)   { return 1.0f / (1.0f + __expf(-x)); }
__device__ __forceinline__ float tanh_f(float x) { return 1.0f - 2.0f / (__expf(2.0f * x) + 1.0f); }

// lgkmcnt-only block barrier: orders LDS ops across waves WITHOUT draining vmcnt.
__device__ __forceinline__ void barrier_lds() {
  asm volatile("s_waitcnt lgkmcnt(0)" ::: "memory");
  __builtin_amdgcn_s_barrier();
  asm volatile("" ::: "memory");
}

// ---------------- prep kernels ----------------

// x [b][t][d] fp32 -> xh tiled f16: xh[t][dg=d/8][b][d%8]
__global__ void prep_x_kernel(const float* __restrict__ x, _Float16* __restrict__ xh) {
  int id = blockIdx.x * blockDim.x + threadIdx.x;   // 64*256*512
  int j = id & 7, b = (id >> 3) & 63, cg = (id >> 9) & 63, t = id >> 15;
  xh[id] = (_Float16)x[((size_t)b * 256 + t) * 512 + cg * 8 + j];
}

// Build MFMA B-fragment layout: dst[((nt*(K/32)+kb)*64 + lane)*8 + j] =
//   src[k = kb*32 + (lane>>4)*8 + j][col = perm(nt*16 + (lane&15))]
__global__ void swizzle_b_kernel(const float* __restrict__ src0, const float* __restrict__ src1,
                                 int k0, int K, int N, int srcStride, int permute,
                                 _Float16* __restrict__ dst) {
  int id = blockIdx.x * blockDim.x + threadIdx.x;
  int total = (N / 16) * (K / 32) * 64;
  if (id >= total) return;
  int lane = id & 63;
  int kb = (id >> 6) % (K / 32);
  int nt = id / ((K / 32) * 64);
  int kbase = kb * 32 + ((lane >> 4) << 3);
  int pc = nt * 16 + (lane & 15);
  int oc = permute ? ((pc & 3) * 1024 + (pc >> 2)) : pc;   // pc = 4*hcol + gate
  f16x8 v;
  #pragma unroll
  for (int j = 0; j < 8; ++j) {
    int k = kbase + j;
    float f = (k < k0) ? src0[(size_t)k * srcStride + oc]
                       : src1[(size_t)(k - k0) * srcStride + oc];
    v[j] = (_Float16)f;
  }
  ((f16x8*)dst)[id] = v;
}

__global__ void prep_small_kernel(const float* __restrict__ b1, const float* __restrict__ b2,
                                  const float* __restrict__ h0,
                                  float* __restrict__ b1p, float* __restrict__ b2p,
                                  _Float16* __restrict__ ys1_0, int* __restrict__ bar) {
  int i = blockIdx.x * blockDim.x + threadIdx.x;
  if (i < 4096) {
    int oc = (i & 3) * 1024 + (i >> 2);
    b1p[i] = b1[oc];
    b2p[i] = b2[oc];
  }
  if (i < 65536) {  // h0 [b][1024] -> tiled [cg][b][8]
    int j = i & 7, b = (i >> 3) & 63, cg = i >> 9;
    ys1_0[i] = (_Float16)h0[b * 1024 + cg * 8 + j];
  }
  if (i < 16384) bar[i] = 0;   // 2 layers x (2 halves x 64 flags x 32-int stride)
}

// Pre-fill h slots 1..256 of both layers with the f16 sentinel 0x7FFF.
__global__ void sentinel_fill_kernel(_Float16* __restrict__ ys1, _Float16* __restrict__ ys2) {
  size_t i = (size_t)blockIdx.x * blockDim.x + threadIdx.x;   // 0 .. 2097151
  uint4 s = {0x7FFF7FFFu, 0x7FFF7FFFu, 0x7FFF7FFFu, 0x7FFF7FFFu};
  ((uint4*)(ys1 + 65536))[i] = s;
  ((uint4*)(ys2 + 65536))[i] = s;
}

// ---------------- x-part gate GEMM ----------------
// xg[((t*256 + gb)*256 + w*64 + lane)] (half4) = x-part pre-activation in MFMA
// C-layout, gb in the OLD 256-block coords (mb=gb&1, nb=gb>>1 over 8-hcol tiles).
__launch_bounds__(256, 2)
__global__ void xg_gemm_kernel(const _Float16* __restrict__ xsrc, size_t xts, int kxb,
                               const _Float16* __restrict__ bfrag, const float* __restrict__ biasp,
                               _Float16* __restrict__ xg) {
  __shared__ _Float16 Bs[2 * 32 * 64 * 8];   // 64 KB max (kxb<=32), 2 n-tiles
  const int tid = threadIdx.x;
  const int lane = tid & 63;
  const int w = tid >> 6;
  const int btc = blockIdx.x >> 8;
  const int gb = blockIdx.x & 255;
  const int mb = gb & 1, nb = gb >> 1;
  const int KB = kxb + 32;
  if (tid == 0)  // purge stale L2 lines (pre-dispatch poison) before cached reads
    (void)__hip_atomic_load((const int*)biasp, __ATOMIC_ACQUIRE, __HIP_MEMORY_SCOPE_AGENT);
  __syncthreads();
  #pragma unroll
  for (int h = 0; h < 2; ++h) {
    const uint4* s = (const uint4*)bfrag + (size_t)((2 * nb + h) * KB) * 64;  // x-part
    uint4* d = (uint4*)Bs + h * 2048;
    for (int i = tid; i < kxb * 64; i += 256) d[i] = s[i];
  }
  __syncthreads();
  const f16x8* Bv = (const f16x8*)Bs;
  const int q = lane >> 4;
  const float bias0 = biasp[(2 * nb + 0) * 16 + (lane & 15)];
  const float bias1 = biasp[(2 * nb + 1) * 16 + (lane & 15)];
  for (int i = 0; i < 32; ++i) {
    int t = btc * 128 + i * 4 + w;
    const f16x8* ax = (const f16x8*)(xsrc + (size_t)t * xts);
    f32x4 acc[4];  // tile index w' = (wn'<<1)|wm'
    acc[0] = (f32x4){bias0, bias0, bias0, bias0};
    acc[1] = (f32x4){bias0, bias0, bias0, bias0};
    acc[2] = (f32x4){bias1, bias1, bias1, bias1};
    acc[3] = (f32x4){bias1, bias1, bias1, bias1};
    #pragma unroll 8
    for (int kb = 0; kb < kxb; ++kb) {
      f16x8 a0 = ax[(kb * 4 + q) * 64 + mb * 32 + (lane & 15)];
      f16x8 a1 = ax[(kb * 4 + q) * 64 + mb * 32 + 16 + (lane & 15)];
      f16x8 b0 = Bv[kb * 64 + lane];
      f16x8 b1v = Bv[2048 + kb * 64 + lane];
      acc[0] = __builtin_amdgcn_mfma_f32_16x16x32_f16(a0, b0, acc[0], 0, 0, 0);
      acc[1] = __builtin_amdgcn_mfma_f32_16x16x32_f16(a1, b0, acc[1], 0, 0, 0);
      acc[2] = __builtin_amdgcn_mfma_f32_16x16x32_f16(a0, b1v, acc[2], 0, 0, 0);
      acc[3] = __builtin_amdgcn_mfma_f32_16x16x32_f16(a1, b1v, acc[3], 0, 0, 0);
    }
    #pragma unroll
    for (int wp = 0; wp < 4; ++wp) {
      f16x4 hv;
      #pragma unroll
      for (int j = 0; j < 4; ++j) hv[j] = (_Float16)acc[wp][j];
      ((f16x4*)xg)[((size_t)t * 256 + gb) * 256 + wp * 64 + lane] = hv;
    }
  }
}

// ---------------- persistent LSTM layer (recurrence only) ----------------
// Grid 128 = mb(2) x nb2(64). Block: batches [32mb,+32) x hcols [16nb2,+16).
// 8 waves: wm=w&1, wn=w>>1 (0..3). h slot (u64): idx = cg*128 + b*2 + half.
// Wave w's staged slice per quarter p: cg = 32p + 4w + i (i=0..3), produced by
// blocks nb2 = 16p + 2w + (i>>1)  => exactly 8 producer flags per wave.
// Per step:
//   poll my 8 flags (agent) -> PLAIN load quarter 0 (L2-cacheable; XCD dedup),
//   sentinel-verify (retry pendings with AGENT bypass loads), stage to As;
//   4 MFMA phases (quarter p+1 plain loads issued before quarter p's MFMAs);
//   gates; publish h patch (agent u64); s_waitcnt vmcnt(0); s_barrier;
//   tid0 flag store (flag now implies h at LLC).
__launch_bounds__(NT, 1)
__global__ void lstm_layer_kernel(const _Float16* __restrict__ xg,
                                  _Float16* hseq, const _Float16* __restrict__ hinit,
                                  const _Float16* __restrict__ bfrag, int kxb,
                                  const float* __restrict__ cin, float* __restrict__ cout,
                                  int* bar) {
  __shared__ _Float16 Bs[4 * 32 * 64 * 8];            // 128 KB U-part B frags (4 n-tiles)
  __shared__ _Float16 As[32 * 32 * 8];                // 16 KB: one feature-quarter of h_t
  __shared__ __align__(16) float gt[8][16 * 20];      // per-wave gate tile (pad 20)
  __shared__ u64 hl[8][16];                           // per-wave h staging (128 B)
  const int tid = threadIdx.x;
  const int lane = tid & 63;
  const int w = tid >> 6;
  const int wm = w & 1, wn = w >> 1;                  // wn in 0..3
  const int mb = blockIdx.x & 1, nb2 = blockIdx.x >> 1;
  const int KB = kxb + 32;

  if (tid == 0)  // purge stale L2 (poison / cross-dispatch) before cached reads
    (void)__hip_atomic_load(&bar[1024], __ATOMIC_ACQUIRE, __HIP_MEMORY_SCOPE_AGENT);
  __syncthreads();

  #pragma unroll
  for (int h = 0; h < 4; ++h) {  // stage U-part fragments for n-tiles 4nb2..4nb2+3
    const uint4* s = (const uint4*)bfrag + (size_t)((4 * nb2 + h) * KB + kxb) * 64;
    uint4* d = (uint4*)Bs + h * 2048;
    for (int i = tid; i < 2048; i += NT) d[i] = s[i];
  }
  __syncthreads();

  const f16x8* Bv = (const f16x8*)Bs;
  const f16x8* Af = (const f16x8*)As;
  u64* As64 = (u64*)As;
  const int q = lane >> 4;
  const int lrow = wm * 16 + (lane & 15);             // local batch row 0..31
  float cc = cin[(size_t)(mb * 32 + wm * 16 + (lane >> 2)) * 1024
                 + nb2 * 16 + wn * 4 + (lane & 3)];
  float* gw = &gt[w][0];
  _Float16* hw = (_Float16*)&hl[w][0];
  // publish target: cols [16nb2+4wn,+4) of batch (mb*32+wm*16+(lane&15))
  const u64 hstIdx = (u64)((2 * nb2 + (wn >> 1)) * 128
                           + (mb * 32 + wm * 16 + (lane & 15)) * 2 + (wn & 1));
  // my 8 producers: nb2' = 16*((lane&7)>>1) + 2*w + (lane&1)  (lanes 0..7 cover all)
  const int* fpoll = bar + (size_t)(mb * 64 + 16 * ((lane & 7) >> 1) + 2 * w + (lane & 1)) * 32;
  int* fown = bar + (size_t)(mb * 64 + nb2) * 32;
  // xg C-fragment coords in the old 256-block layout:
  const int gbm = ((2 * nb2 + (wn >> 1)) << 1) | mb;
  const int wq = wm + 2 * (wn & 1);
  const size_t xgBase = (size_t)gbm * 256 + wq * 64 + lane;

  u64 pre[4];                                         // next-quarter staging regs
  for (int t = 0; t < 256; ++t) {
    f16x4 xgv = ((const f16x4*)xg)[(size_t)t * 65536 + xgBase];  // prefetch
    const u64* Sg = (const u64*)((t == 0) ? hinit : (hseq + (size_t)t * 65536));
    // ---- poll my wave's 8 producers (hint flags; drain=>data at LLC) ----
    if (t) {
      for (;;) {
        int v = __hip_atomic_load(fpoll, __ATOMIC_RELAXED, __HIP_MEMORY_SCOPE_AGENT);
        if (__all(v >= t)) break;
        __builtin_amdgcn_s_sleep(1);
      }
      asm volatile("" ::: "memory");  // keep data loads below the poll
    }
    // ---- phase 0: PLAIN load + verify + stage quarter 0 ----
    {
      const u64* src = Sg + (size_t)(w * 4) * 128 + mb * 64 + lane;
      #pragma unroll
      for (int i = 0; i < 4; ++i) pre[i] = src[(size_t)i * 128];   // L2-cacheable
      for (;;) {
        unsigned np = 0;
        #pragma unroll
        for (int i = 0; i < 4; ++i)
          np |= (((unsigned)pre[i] == 0x7FFF7FFFu) ? 1u : 0u) << i;
        if (__all(np == 0)) break;
        __builtin_amdgcn_s_sleep(1);
        #pragma unroll
        for (int i = 0; i < 4; ++i)   // retry pendings with AGENT bypass (truth)
          if ((np >> i) & 1)
            pre[i] = __hip_atomic_load(src + (size_t)i * 128, __ATOMIC_RELAXED, __HIP_MEMORY_SCOPE_AGENT);
      }
      #pragma unroll
      for (int i = 0; i < 4; ++i) As64[(w * 4 + i) * 64 + lane] = pre[i];
    }
    barrier_lds();                                    // quarter 0 staged
    // ---- 4 MFMA phases; quarter p+1 plain loads fly under quarter p's MFMAs ----
    f32x4 acc = {(float)xgv[0], (float)xgv[1], (float)xgv[2], (float)xgv[3]};
    f32x4 acc2 = {0.f, 0.f, 0.f, 0.f};
    #pragma unroll
    for (int p = 0; p < 4; ++p) {
      if (p < 3) {  // issue next quarter's PLAIN loads into regs
        const u64* src = Sg + (size_t)((p + 1) * 32 + w * 4) * 128 + mb * 64 + lane;
        #pragma unroll
        for (int i = 0; i < 4; ++i) pre[i] = src[(size_t)i * 128];
      }
      #pragma unroll
      for (int j = 0; j < 8; j += 2) {   // kb = 8p+j; even->acc, odd->acc2 (R9 order)
        acc  = __builtin_amdgcn_mfma_f32_16x16x32_f16(Af[(4 * j + q) * 32 + lrow],
                                                      Bv[(wn * 32 + 8 * p + j) * 64 + lane],
                                                      acc, 0, 0, 0);
        acc2 = __builtin_amdgcn_mfma_f32_16x16x32_f16(Af[(4 * j + 4 + q) * 32 + lrow],
                                                      Bv[(wn * 32 + 8 * p + j + 1) * 64 + lane],
                                                      acc2, 0, 0, 0);
      }
      if (p < 3) {
        barrier_lds();                                // all waves done reading quarter p
        const u64* src = Sg + (size_t)((p + 1) * 32 + w * 4) * 128 + mb * 64 + lane;
        for (;;) {
          unsigned np = 0;
          #pragma unroll
          for (int i = 0; i < 4; ++i)
            np |= (((unsigned)pre[i] == 0x7FFF7FFFu) ? 1u : 0u) << i;
          if (__all(np == 0)) break;
          __builtin_amdgcn_s_sleep(1);
          #pragma unroll
          for (int i = 0; i < 4; ++i)
            if ((np >> i) & 1)
              pre[i] = __hip_atomic_load(src + (size_t)i * 128, __ATOMIC_RELAXED, __HIP_MEMORY_SCOPE_AGENT);
        }
        #pragma unroll
        for (int i = 0; i < 4; ++i) As64[(w * 4 + i) * 64 + lane] = pre[i];
        barrier_lds();                                // quarter p+1 staged
      }
    }
    #pragma unroll
    for (int r = 0; r < 4; ++r) acc[r] += acc2[r];
    // ---- wave-local gate regroup: write C rows, read this lane's cell ----
    #pragma unroll
    for (int r = 0; r < 4; ++r) gw[(q * 4 + r) * 20 + (lane & 15)] = acc[r];
    float4 gv = *(float4*)&gw[(lane >> 2) * 20 + (lane & 3) * 4];
    cc = sigm(gv.y) * cc + sigm(gv.x) * tanh_f(gv.z);
    float hn = sigm(gv.w) * tanh_f(cc);
    hw[lane] = (_Float16)hn;                          // hw[4*b4 + c]
    u64 hv = hl[w][lane & 15];                        // 8B = this wave's 4 cols of batch (lane&15)
    if (lane < 16)
      __hip_atomic_store((u64*)(hseq + (size_t)(t + 1) * 65536) + hstIdx, hv,
                         __ATOMIC_RELAXED, __HIP_MEMORY_SCOPE_AGENT);
    // drain this wave's h stores to the coherence point, then block-wide barrier
    // (doubles as the As-protection barrier), then the flag.
    asm volatile("s_waitcnt vmcnt(0)" ::: "memory");
    __builtin_amdgcn_s_barrier();
    asm volatile("" ::: "memory");
    if (t < 255 && tid == 0)                          // flag now implies h at LLC
      __hip_atomic_store(fown, t + 1, __ATOMIC_RELAXED, __HIP_MEMORY_SCOPE_AGENT);
  }
  if (cout)
    cout[(size_t)(mb * 32 + wm * 16 + (lane >> 2)) * 1024
         + nb2 * 16 + wn * 4 + (lane & 3)] = cc;
}

// ---------------- FC head ----------------

// Y1[b][u][j] = ys2[u+1][b][:] @ fc1_w[:, j] + fc1_b[j]   (16384x1024 @ 1024x512)
__launch_bounds__(256, 1)
__global__ void fc1_gemm_kernel(const _Float16* __restrict__ ys2, const _Float16* __restrict__ wfrag,
                                const float* __restrict__ fc1b, float* __restrict__ Y1) {
  const int mb = blockIdx.x >> 3;
  const int nb = blockIdx.x & 7;
  const int tid = threadIdx.x;
  const int lane = tid & 63;
  const int w = tid >> 6;
  const int q = lane >> 4;
  const int R0 = mb * 64 + w * 16;
  const int arow = R0 + (lane & 15);           // row = u*64 + b
  const int u = arow >> 6;
  const int b = arow & 63;
  const f16x8* A = (const f16x8*)(ys2 + (size_t)(u + 1) * 65536);  // tiled [cg][b][8]
  const f16x8* W = (const f16x8*)wfrag;
  f32x4 acc[4];
  #pragma unroll
  for (int n = 0; n < 4; ++n) acc[n] = (f32x4){0.f, 0.f, 0.f, 0.f};
  #pragma unroll 4
  for (int kb = 0; kb < 32; ++kb) {
    f16x8 a = A[(kb * 4 + q) * 64 + b];
    #pragma unroll
    for (int n = 0; n < 4; ++n)
      acc[n] = __builtin_amdgcn_mfma_f32_16x16x32_f16(a, W[(((nb * 4 + n) * 32) + kb) * 64 + lane],
                                                      acc[n], 0, 0, 0);
  }
  const int rb = R0 + (q << 2);
  #pragma unroll
  for (int n = 0; n < 4; ++n) {
    int col = nb * 64 + n * 16 + (lane & 15);
    float bias = fc1b[col];
    #pragma unroll
    for (int r = 0; r < 4; ++r) {
      int R = rb + r;
      Y1[((size_t)(R & 63) * 256 + (R >> 6)) * 512 + col] = acc[n][r] + bias;
    }
  }
}

// FC2 partial reduction: 256 K-chunks of 512; part[kc][b][36]
__global__ void fc2_partial_kernel(const float* __restrict__ Y1, const float* __restrict__ fc2w,
                                   float* __restrict__ part) {
  int kc = blockIdx.x;
  int tid = threadIdx.x;
  int b = tid >> 2, qq = tid & 3;
  const float* y = Y1 + (size_t)b * 131072 + (size_t)kc * 512;
  const float* wbase = fc2w + (size_t)kc * 512 * 36 + qq * 9;
  float acc[9];
  #pragma unroll
  for (int j = 0; j < 9; ++j) acc[j] = 0.f;
  for (int k = 0; k < 512; ++k) {
    float yv = y[k];
    const float* wr = wbase + (size_t)k * 36;
    #pragma unroll
    for (int j = 0; j < 9; ++j) acc[j] = fmaf(yv, wr[j], acc[j]);
  }
  float* o = part + ((size_t)kc * 64 + b) * 36 + qq * 9;
  #pragma unroll
  for (int j = 0; j < 9; ++j) o[j] = acc[j];
}

// Parallel kc-reduction of part -> z2g[b*36+m]
__global__ void fc2_reduce_kernel(const float* __restrict__ part, const float* __restrict__ fc2b,
                                  float* __restrict__ z2g) {
  int idx = blockIdx.x * blockDim.x + threadIdx.x;   // 9*256 >= 2304
  if (idx >= 2304) return;
  int b = idx / 36, m = idx % 36;
  float s = fc2b[m];
  for (int kc = 0; kc < 256; ++kc) s += part[((size_t)kc * 64 + b) * 36 + m];
  z2g[idx] = s;
}

__global__ void fc_final_kernel(const float* __restrict__ z2g,
                                const float* __restrict__ fc3w, const float* __restrict__ fc3b,
                                const float* __restrict__ fc4w, const float* __restrict__ fc4b,
                                float* __restrict__ out) {
  __shared__ float z2[64 * 36];
  __shared__ float z3[64 * 6];
  int tid = threadIdx.x;  // 384
  for (int idx = tid; idx < 64 * 36; idx += 384) z2[idx] = z2g[idx];
  __syncthreads();
  {
    int b = tid / 6, n = tid % 6;
    float s = fc3b[n];
    #pragma unroll 4
    for (int m = 0; m < 36; ++m) s += z2[b * 36 + m] * fc3w[m * 6 + n];
    z3[tid] = s;
  }
  __syncthreads();
  {
    int b = tid / 6, n = tid % 6;
    float s = fc4b[n];
    #pragma unroll
    for (int m = 0; m < 6; ++m) s += z3[b * 6 + m] * fc4w[m * 6 + n];
    out[tid] = fmaxf(s, 0.0f);
  }
}

// ---------------- host ----------------

extern "C" void kernel_launch(void* const* d_in, const int* in_sizes, int n_in,
                              void* d_out, int out_size, void* d_ws, size_t ws_size,
                              hipStream_t stream) {
  const float* x    = (const float*)d_in[0];
  const float* h0   = (const float*)d_in[1];
  const float* c0   = (const float*)d_in[2];
  const float* W1   = (const float*)d_in[3];
  const float* U1   = (const float*)d_in[4];
  const float* b1   = (const float*)d_in[5];
  const float* W2   = (const float*)d_in[6];
  const float* U2   = (const float*)d_in[7];
  const float* b2   = (const float*)d_in[8];
  const float* fc1w = (const float*)d_in[9];
  const float* fc1b = (const float*)d_in[10];
  const float* fc2w = (const float*)d_in[11];
  const float* fc2b = (const float*)d_in[12];
  const float* fc3w = (const float*)d_in[13];
  const float* fc3b = (const float*)d_in[14];
  const float* fc4w = (const float*)d_in[15];
  const float* fc4b = (const float*)d_in[16];
  float* out = (float*)d_out;

  char* p = (char*)d_ws;
  auto alloc = [&](size_t bytes) { char* r = p; p += (bytes + 255) & ~(size_t)255; return r; };
  _Float16* xh    = (_Float16*)alloc(8388608ull * 2);        // x tiled f16 [t][dg][b][8]
  _Float16* wu1f  = (_Float16*)alloc(1536ull * 4096 * 2);    // [W1;U1] B-fragments, permuted cols
  _Float16* wu2f  = (_Float16*)alloc(2048ull * 4096 * 2);    // [W2;U2]
  _Float16* fc1wf = (_Float16*)alloc(1024ull * 512 * 2);     // fc1_w B-fragments
  float* b1p      = (float*)alloc(4096 * 4);
  float* b2p      = (float*)alloc(4096 * 4);
  _Float16* ys1   = (_Float16*)alloc(257ull * 65536 * 2);    // h1 slots, tiled: [0]=h0, [t+1]=h1_t
  _Float16* ys2   = (_Float16*)alloc(257ull * 65536 * 2);    // h2 slots, tiled
  float* cfin     = (float*)alloc(65536 * 4);                // c1 final [b][h] fp32
  _Float16* xg    = (_Float16*)alloc(256ull * 65536 * 4 * 2);// 128 MB: x-part gates
  float* part     = (float*)alloc(256ull * 64 * 36 * 4);     // FC2 partials
  int* bar        = (int*)alloc(16384 * 4);                  // 2 layers x 8192-int flag region
  float* z2g      = (float*)alloc(2304 * 4);                 // FC2 reduced
  float* Y1       = (float*)xg;                              // FC1 out aliases xg (dead by then)
  (void)in_sizes; (void)n_in; (void)out_size; (void)ws_size;

  prep_x_kernel<<<8388608 / 256, 256, 0, stream>>>(x, xh);
  swizzle_b_kernel<<<(256 * 48 * 64) / 256, 256, 0, stream>>>(W1, U1, 512, 1536, 4096, 4096, 1, wu1f);
  swizzle_b_kernel<<<(256 * 64 * 64) / 256, 256, 0, stream>>>(W2, U2, 1024, 2048, 4096, 4096, 1, wu2f);
  swizzle_b_kernel<<<(32 * 32 * 64) / 256, 256, 0, stream>>>(fc1w, fc1w, 1024, 1024, 512, 512, 0, fc1wf);
  prep_small_kernel<<<256, 256, 0, stream>>>(b1, b2, h0, b1p, b2p, ys1, bar);
  sentinel_fill_kernel<<<8192, 256, 0, stream>>>(ys1, ys2);  // slots 1..256 := 0x7FFF sentinel

  // Layer 1: xg1 = x@W1+b1, then recurrence (h slot0 = h0; c: c0 -> cfin)
  xg_gemm_kernel<<<512, 256, 0, stream>>>(xh, (size_t)32768, 16, wu1f, b1p, xg);
  lstm_layer_kernel<<<128, NT, 0, stream>>>(xg, ys1, ys1, wu1f, 16, c0, cfin, bar);
  // Layer 2: xg2 = ys1@W2+b2 (ys1 fully materialized), then recurrence
  xg_gemm_kernel<<<512, 256, 0, stream>>>(ys1 + 65536, (size_t)65536, 32, wu2f, b2p, xg);
  lstm_layer_kernel<<<128, NT, 0, stream>>>(xg, ys2, ys1 + (size_t)256 * 65536, wu2f, 32,
                                            cfin, nullptr, bar + 8192);

  fc1_gemm_kernel<<<2048, 256, 0, stream>>>(ys2, fc1wf, fc1b, Y1);
  fc2_partial_kernel<<<256, 256, 0, stream>>>(Y1, fc2w, part);
  fc2_reduce_kernel<<<9, 256, 0, stream>>>(part, fc2b, z2g);
  fc_final_kernel<<<1, 384, 0, stream>>>(z2g, fc3w, fc3b, fc4w, fc4b, out);
}

// Round 7
// 2994.127 us; speedup vs baseline: 1.1136x; 1.1136x over previous
//
#include <hip/hip_runtime.h>

// ComplexModel: 2-layer LSTM (B=64,T=256,D=512,H=1024) + FC head, MI355X gfx950.
// R14 = R9 (best measured: 1068us/lstm) + depth-4 xg prefetch ring:
//  - R11 (traffic/2) and R13 (L2-cacheable loads) were both null/negative ->
//    broadcast read path is NOT the wall. Remaining suspect: per-step xg load
//    (1KB/block from HBM, issued in a 256-block burst at the sync point,
//    consumed ~1us later) stalls + jitters; the producer-consumer lockstep
//    amplifies any per-block jitter into global rate loss.
//  - R14 holds 4 steps of xg in VGPRs (f16x4 ring, static indices via
//    #pragma unroll 4): consume xb[t&3], reissue for t+4 => ~16us of latency
//    cover, zero burst alignment with the sync point.
//  - lstm structure otherwise IDENTICAL to R9 (256 blocks x 4 waves, one-shot
//    64KB As staging, 2 barriers/step, hint flags + sentinel truth, no vmcnt
//    drain). Math bit-identical -> absmax must stay 7.629395e-06.
//  - FC head keeps the R10+ parallel fc2_reduce split.

#define NT 256

typedef _Float16 f16x8 __attribute__((ext_vector_type(8)));
typedef _Float16 f16x4 __attribute__((ext_vector_type(4)));
typedef float f32x4 __attribute__((ext_vector_type(4)));
typedef unsigned long long u64;

__device__ __forceinline__ float sigm(float x)   { return 1.0f / (1.0f + __expf(-x)); }
__device__ __forceinline__ float tanh_f(float x) { return 1.0f - 2.0f / (__expf(2.0f * x) + 1.0f); }

// lgkmcnt-only block barrier: orders LDS ops across waves WITHOUT draining vmcnt
// (so in-flight global h stores / xg prefetches keep flying across it).
__device__ __forceinline__ void barrier_lds() {
  asm volatile("s_waitcnt lgkmcnt(0)" ::: "memory");
  __builtin_amdgcn_s_barrier();
  asm volatile("" ::: "memory");
}

// ---------------- prep kernels ----------------

// x [b][t][d] fp32 -> xh tiled f16: xh[t][dg=d/8][b][d%8]
__global__ void prep_x_kernel(const float* __restrict__ x, _Float16* __restrict__ xh) {
  int id = blockIdx.x * blockDim.x + threadIdx.x;   // 64*256*512
  int j = id & 7, b = (id >> 3) & 63, cg = (id >> 9) & 63, t = id >> 15;
  xh[id] = (_Float16)x[((size_t)b * 256 + t) * 512 + cg * 8 + j];
}

// Build MFMA B-fragment layout: dst[((nt*(K/32)+kb)*64 + lane)*8 + j] =
//   src[k = kb*32 + (lane>>4)*8 + j][col = perm(nt*16 + (lane&15))]
__global__ void swizzle_b_kernel(const float* __restrict__ src0, const float* __restrict__ src1,
                                 int k0, int K, int N, int srcStride, int permute,
                                 _Float16* __restrict__ dst) {
  int id = blockIdx.x * blockDim.x + threadIdx.x;
  int total = (N / 16) * (K / 32) * 64;
  if (id >= total) return;
  int lane = id & 63;
  int kb = (id >> 6) % (K / 32);
  int nt = id / ((K / 32) * 64);
  int kbase = kb * 32 + ((lane >> 4) << 3);
  int pc = nt * 16 + (lane & 15);
  int oc = permute ? ((pc & 3) * 1024 + (pc >> 2)) : pc;   // pc = 4*hcol + gate
  f16x8 v;
  #pragma unroll
  for (int j = 0; j < 8; ++j) {
    int k = kbase + j;
    float f = (k < k0) ? src0[(size_t)k * srcStride + oc]
                       : src1[(size_t)(k - k0) * srcStride + oc];
    v[j] = (_Float16)f;
  }
  ((f16x8*)dst)[id] = v;
}

__global__ void prep_small_kernel(const float* __restrict__ b1, const float* __restrict__ b2,
                                  const float* __restrict__ h0,
                                  float* __restrict__ b1p, float* __restrict__ b2p,
                                  _Float16* __restrict__ ys1_0, int* __restrict__ bar) {
  int i = blockIdx.x * blockDim.x + threadIdx.x;
  if (i < 4096) {
    int oc = (i & 3) * 1024 + (i >> 2);
    b1p[i] = b1[oc];
    b2p[i] = b2[oc];
  }
  if (i < 65536) {  // h0 [b][1024] -> tiled [cg][b][8]
    int j = i & 7, b = (i >> 3) & 63, cg = i >> 9;
    ys1_0[i] = (_Float16)h0[b * 1024 + cg * 8 + j];
  }
  if (i < 16384) bar[i] = 0;   // 2 layers x 2 halves x 128 flags x 32-int stride
}

// Pre-fill h slots 1..256 of both layers with the f16 sentinel 0x7FFF.
__global__ void sentinel_fill_kernel(_Float16* __restrict__ ys1, _Float16* __restrict__ ys2) {
  size_t i = (size_t)blockIdx.x * blockDim.x + threadIdx.x;   // 0 .. 2097151
  uint4 s = {0x7FFF7FFFu, 0x7FFF7FFFu, 0x7FFF7FFFu, 0x7FFF7FFFu};
  ((uint4*)(ys1 + 65536))[i] = s;
  ((uint4*)(ys2 + 65536))[i] = s;
}

// ---------------- x-part gate GEMM ----------------
// xg[((t*256 + gb)*256 + w*64 + lane)] (half4) = x-part pre-activation in the exact
// MFMA C-layout the lstm kernel's wave w / lane expects. gb == lstm blockIdx.
__launch_bounds__(256, 2)
__global__ void xg_gemm_kernel(const _Float16* __restrict__ xsrc, size_t xts, int kxb,
                               const _Float16* __restrict__ bfrag, const float* __restrict__ biasp,
                               _Float16* __restrict__ xg) {
  __shared__ _Float16 Bs[2 * 32 * 64 * 8];   // 64 KB max (kxb<=32), 2 n-tiles
  const int tid = threadIdx.x;
  const int lane = tid & 63;
  const int w = tid >> 6;
  const int btc = blockIdx.x >> 8;
  const int gb = blockIdx.x & 255;
  const int mb = gb & 1, nb = gb >> 1;
  const int KB = kxb + 32;
  if (tid == 0)  // purge stale L2 lines (pre-dispatch poison) before cached reads
    (void)__hip_atomic_load((const int*)biasp, __ATOMIC_ACQUIRE, __HIP_MEMORY_SCOPE_AGENT);
  __syncthreads();
  #pragma unroll
  for (int h = 0; h < 2; ++h) {
    const uint4* s = (const uint4*)bfrag + (size_t)((2 * nb + h) * KB) * 64;  // x-part
    uint4* d = (uint4*)Bs + h * 2048;
    for (int i = tid; i < kxb * 64; i += NT) d[i] = s[i];
  }
  __syncthreads();
  const f16x8* Bv = (const f16x8*)Bs;
  const int q = lane >> 4;
  const float bias0 = biasp[(2 * nb + 0) * 16 + (lane & 15)];
  const float bias1 = biasp[(2 * nb + 1) * 16 + (lane & 15)];
  for (int i = 0; i < 32; ++i) {
    int t = btc * 128 + i * 4 + w;
    const f16x8* ax = (const f16x8*)(xsrc + (size_t)t * xts);
    f32x4 acc[4];  // tile index w' = (wn'<<1)|wm'
    acc[0] = (f32x4){bias0, bias0, bias0, bias0};
    acc[1] = (f32x4){bias0, bias0, bias0, bias0};
    acc[2] = (f32x4){bias1, bias1, bias1, bias1};
    acc[3] = (f32x4){bias1, bias1, bias1, bias1};
    #pragma unroll 8
    for (int kb = 0; kb < kxb; ++kb) {
      f16x8 a0 = ax[(kb * 4 + q) * 64 + mb * 32 + (lane & 15)];
      f16x8 a1 = ax[(kb * 4 + q) * 64 + mb * 32 + 16 + (lane & 15)];
      f16x8 b0 = Bv[kb * 64 + lane];
      f16x8 b1v = Bv[2048 + kb * 64 + lane];
      acc[0] = __builtin_amdgcn_mfma_f32_16x16x32_f16(a0, b0, acc[0], 0, 0, 0);
      acc[1] = __builtin_amdgcn_mfma_f32_16x16x32_f16(a1, b0, acc[1], 0, 0, 0);
      acc[2] = __builtin_amdgcn_mfma_f32_16x16x32_f16(a0, b1v, acc[2], 0, 0, 0);
      acc[3] = __builtin_amdgcn_mfma_f32_16x16x32_f16(a1, b1v, acc[3], 0, 0, 0);
    }
    #pragma unroll
    for (int wp = 0; wp < 4; ++wp) {
      f16x4 hv;
      #pragma unroll
      for (int j = 0; j < 4; ++j) hv[j] = (_Float16)acc[wp][j];
      ((f16x4*)xg)[((size_t)t * 256 + gb) * 256 + wp * 64 + lane] = hv;
    }
  }
}

// ---------------- persistent LSTM layer (recurrence only) ----------------
// R9 structure. Grid 256 = mb(2) x nb(128). Block: batches [32mb,+32) x hcols
// [8nb,+8). Waves: wm=w&1, wn=w>>1. h slot layout: [cg=col/8][b][col%8].
// Per step:
//   0. consume xg from the depth-4 VGPR ring; reissue slot for t+4.
//   1. wave w polls its quarter's 32 flags (1 u32 agent load/lane), then loads
//      its 32 h data words (agent u64, sentinel verify) -> ds_write As.
//   2. barrier_lds; 32 MFMAs (2 interleaved accumulators); gate regroup;
//      c/h update; publish 128B h patch (16 lanes x relaxed agent u64);
//      barrier_lds; tid0 stores hint flag := t+1 (no vmcnt drain).
__launch_bounds__(NT, 1)
__global__ void lstm_layer_kernel(const _Float16* __restrict__ xg,
                                  _Float16* hseq, const _Float16* __restrict__ hinit,
                                  const _Float16* __restrict__ bfrag, int kxb,
                                  const float* __restrict__ cin, float* __restrict__ cout,
                                  int* bar) {
  __shared__ _Float16 Bs[2 * 32 * 64 * 8];            // 64 KB U-part B fragments
  __shared__ _Float16 As[128 * 32 * 8];               // 64 KB staged h_t [cg][b32][8]
  __shared__ __align__(16) float gt[4][16 * 20];      // per-wave gate tile (pad 20)
  __shared__ u64 hl[4][16];                           // per-wave h staging (128 B)
  const int tid = threadIdx.x;
  const int lane = tid & 63;
  const int w = tid >> 6;
  const int wm = w & 1, wn = w >> 1;
  const int blk = blockIdx.x;
  const int mb = blk & 1, nb = blk >> 1;
  const int KB = kxb + 32;

  if (tid == 0)  // purge stale L2 (poison / cross-dispatch) before cached reads
    (void)__hip_atomic_load(&bar[1024], __ATOMIC_ACQUIRE, __HIP_MEMORY_SCOPE_AGENT);
  __syncthreads();

  #pragma unroll
  for (int h = 0; h < 2; ++h) {  // stage U-part fragments
    const uint4* s = (const uint4*)bfrag + (size_t)((2 * nb + h) * KB + kxb) * 64;
    uint4* d = (uint4*)Bs + h * 2048;
    for (int i = tid; i < 2048; i += NT) d[i] = s[i];
  }
  __syncthreads();

  const f16x8* Bv = (const f16x8*)Bs;
  const f16x8* Af = (const f16x8*)As;
  u64* As64 = (u64*)As;
  const int q = lane >> 4;
  const int lrow = wm * 16 + (lane & 15);             // local batch row 0..31
  float cc = cin[(size_t)(mb * 32 + wm * 16 + (lane >> 2)) * 1024 + nb * 8 + wn * 4 + (lane & 3)];
  float* gw = &gt[w][0];
  _Float16* hw = (_Float16*)&hl[w][0];
  const u64 hstIdx = (u64)(nb * 128 + (mb * 32 + wm * 16 + (lane & 15)) * 2 + wn);
  int* fbase = bar + mb * 4096;                       // this half's 128 padded flags
  const int* fpoll = fbase + (size_t)(w * 32 + (lane & 31)) * 32;  // my quarter's producers
  int* fown = fbase + nb * 32;
  const f16x4* xgp = (const f16x4*)xg;
  const size_t xgBase = (size_t)blk * 256 + w * 64 + lane;

  // depth-4 xg prefetch ring (static indices via unroll-4 below)
  f16x4 xb[4];
  #pragma unroll
  for (int i = 0; i < 4; ++i)
    xb[i] = xgp[(size_t)i * 65536 + xgBase];

  #pragma unroll 4
  for (int t = 0; t < 256; ++t) {
    f16x4 xgv = xb[t & 3];                            // loaded >=4 steps ago
    if (t + 4 < 256)
      xb[t & 3] = xgp[(size_t)(t + 4) * 65536 + xgBase];  // reissue ring slot
    // ---- wait for my quarter's producers (hint flags; 1 load/lane/round) ----
    if (t) {
      for (;;) {
        int v = __hip_atomic_load(fpoll, __ATOMIC_RELAXED, __HIP_MEMORY_SCOPE_AGENT);
        if (__all(v >= t)) break;
        __builtin_amdgcn_s_sleep(1);
      }
      asm volatile("" ::: "memory");  // keep data loads below the poll
    }
    // ---- one-shot load + sentinel verify of my cg quarter of h_t ----
    // u64 index within slot: cg*128 + mb*64 + lane
    const u64* hp = (const u64*)((t == 0) ? hinit : (hseq + (size_t)t * 65536))
                  + (size_t)(w * 32) * 128 + mb * 64 + lane;
    u64 hvv[32];
    #pragma unroll
    for (int i = 0; i < 32; ++i)
      hvv[i] = __hip_atomic_load(hp + (size_t)i * 128, __ATOMIC_RELAXED, __HIP_MEMORY_SCOPE_AGENT);
    for (;;) {
      unsigned np = 0;
      #pragma unroll
      for (int i = 0; i < 32; ++i)
        np |= (((unsigned)hvv[i] == 0x7FFF7FFFu) ? 1u : 0u) << i;  // low32 sentinel check suffices
      if (__all(np == 0)) break;
      __builtin_amdgcn_s_sleep(1);
      #pragma unroll
      for (int i = 0; i < 32; ++i)
        if ((np >> i) & 1)
          hvv[i] = __hip_atomic_load(hp + (size_t)i * 128, __ATOMIC_RELAXED, __HIP_MEMORY_SCOPE_AGENT);
    }
    #pragma unroll
    for (int i = 0; i < 32; ++i) As64[(w * 32 + i) * 64 + lane] = hvv[i];
    barrier_lds();                                    // staging visible to all waves
    // ---- gates (2 interleaved accumulators to halve the MFMA dep chain) ----
    f32x4 acc = {(float)xgv[0], (float)xgv[1], (float)xgv[2], (float)xgv[3]};
    f32x4 acc2 = {0.f, 0.f, 0.f, 0.f};
    #pragma unroll 8
    for (int kb = 0; kb < 16; ++kb) {
      acc  = __builtin_amdgcn_mfma_f32_16x16x32_f16(Af[((2 * kb) * 4 + q) * 32 + lrow],
                                                    Bv[(wn * 32 + 2 * kb) * 64 + lane], acc, 0, 0, 0);
      acc2 = __builtin_amdgcn_mfma_f32_16x16x32_f16(Af[((2 * kb + 1) * 4 + q) * 32 + lrow],
                                                    Bv[(wn * 32 + 2 * kb + 1) * 64 + lane], acc2, 0, 0, 0);
    }
    #pragma unroll
    for (int r = 0; r < 4; ++r) acc[r] += acc2[r];
    // wave-local gate regroup: write C rows, read this lane's cell (i,f,g,o)
    #pragma unroll
    for (int r = 0; r < 4; ++r) gw[(q * 4 + r) * 20 + (lane & 15)] = acc[r];
    float4 gv = *(float4*)&gw[(lane >> 2) * 20 + (lane & 3) * 4];
    cc = sigm(gv.y) * cc + sigm(gv.x) * tanh_f(gv.z);
    float hn = sigm(gv.w) * tanh_f(cc);
    hw[lane] = (_Float16)hn;                          // hw[4*b4 + c]
    u64 hv = hl[w][lane & 15];                        // 8B = cols [wn*4,+4) of batch (lane&15)
    if (lane < 16)
      __hip_atomic_store((u64*)(hseq + (size_t)(t + 1) * 65536) + hstIdx, hv,
                         __ATOMIC_RELAXED, __HIP_MEMORY_SCOPE_AGENT);
    barrier_lds();                                    // all 4 waves' stores ISSUED; As reusable
    if (t < 255 && tid == 0)                          // hint flag; may race ahead of data
      __hip_atomic_store(fown, t + 1, __ATOMIC_RELAXED, __HIP_MEMORY_SCOPE_AGENT);
  }
  if (cout)
    cout[(size_t)(mb * 32 + wm * 16 + (lane >> 2)) * 1024 + nb * 8 + wn * 4 + (lane & 3)] = cc;
}

// ---------------- FC head ----------------

// Y1[b][u][j] = ys2[u+1][b][:] @ fc1_w[:, j] + fc1_b[j]   (16384x1024 @ 1024x512)
__launch_bounds__(256, 1)
__global__ void fc1_gemm_kernel(const _Float16* __restrict__ ys2, const _Float16* __restrict__ wfrag,
                                const float* __restrict__ fc1b, float* __restrict__ Y1) {
  const int mb = blockIdx.x >> 3;
  const int nb = blockIdx.x & 7;
  const int tid = threadIdx.x;
  const int lane = tid & 63;
  const int w = tid >> 6;
  const int q = lane >> 4;
  const int R0 = mb * 64 + w * 16;
  const int arow = R0 + (lane & 15);           // row = u*64 + b
  const int u = arow >> 6;
  const int b = arow & 63;
  const f16x8* A = (const f16x8*)(ys2 + (size_t)(u + 1) * 65536);  // tiled [cg][b][8]
  const f16x8* W = (const f16x8*)wfrag;
  f32x4 acc[4];
  #pragma unroll
  for (int n = 0; n < 4; ++n) acc[n] = (f32x4){0.f, 0.f, 0.f, 0.f};
  #pragma unroll 4
  for (int kb = 0; kb < 32; ++kb) {
    f16x8 a = A[(kb * 4 + q) * 64 + b];
    #pragma unroll
    for (int n = 0; n < 4; ++n)
      acc[n] = __builtin_amdgcn_mfma_f32_16x16x32_f16(a, W[(((nb * 4 + n) * 32) + kb) * 64 + lane],
                                                      acc[n], 0, 0, 0);
  }
  const int rb = R0 + (q << 2);
  #pragma unroll
  for (int n = 0; n < 4; ++n) {
    int col = nb * 64 + n * 16 + (lane & 15);
    float bias = fc1b[col];
    #pragma unroll
    for (int r = 0; r < 4; ++r) {
      int R = rb + r;
      Y1[((size_t)(R & 63) * 256 + (R >> 6)) * 512 + col] = acc[n][r] + bias;
    }
  }
}

// FC2 partial reduction: 256 K-chunks of 512; part[kc][b][36]
__global__ void fc2_partial_kernel(const float* __restrict__ Y1, const float* __restrict__ fc2w,
                                   float* __restrict__ part) {
  int kc = blockIdx.x;
  int tid = threadIdx.x;
  int b = tid >> 2, qq = tid & 3;
  const float* y = Y1 + (size_t)b * 131072 + (size_t)kc * 512;
  const float* wbase = fc2w + (size_t)kc * 512 * 36 + qq * 9;
  float acc[9];
  #pragma unroll
  for (int j = 0; j < 9; ++j) acc[j] = 0.f;
  for (int k = 0; k < 512; ++k) {
    float yv = y[k];
    const float* wr = wbase + (size_t)k * 36;
    #pragma unroll
    for (int j = 0; j < 9; ++j) acc[j] = fmaf(yv, wr[j], acc[j]);
  }
  float* o = part + ((size_t)kc * 64 + b) * 36 + qq * 9;
  #pragma unroll
  for (int j = 0; j < 9; ++j) o[j] = acc[j];
}

// Parallel kc-reduction of part -> z2g[b*36+m]
__global__ void fc2_reduce_kernel(const float* __restrict__ part, const float* __restrict__ fc2b,
                                  float* __restrict__ z2g) {
  int idx = blockIdx.x * blockDim.x + threadIdx.x;   // 9*256 >= 2304
  if (idx >= 2304) return;
  int b = idx / 36, m = idx % 36;
  float s = fc2b[m];
  for (int kc = 0; kc < 256; ++kc) s += part[((size_t)kc * 64 + b) * 36 + m];
  z2g[idx] = s;
}

__global__ void fc_final_kernel(const float* __restrict__ z2g,
                                const float* __restrict__ fc3w, const float* __restrict__ fc3b,
                                const float* __restrict__ fc4w, const float* __restrict__ fc4b,
                                float* __restrict__ out) {
  __shared__ float z2[64 * 36];
  __shared__ float z3[64 * 6];
  int tid = threadIdx.x;  // 384
  for (int idx = tid; idx < 64 * 36; idx += 384) z2[idx] = z2g[idx];
  __syncthreads();
  {
    int b = tid / 6, n = tid % 6;
    float s = fc3b[n];
    #pragma unroll 4
    for (int m = 0; m < 36; ++m) s += z2[b * 36 + m] * fc3w[m * 6 + n];
    z3[tid] = s;
  }
  __syncthreads();
  {
    int b = tid / 6, n = tid % 6;
    float s = fc4b[n];
    #pragma unroll
    for (int m = 0; m < 6; ++m) s += z3[b * 6 + m] * fc4w[m * 6 + n];
    out[tid] = fmaxf(s, 0.0f);
  }
}

// ---------------- host ----------------

extern "C" void kernel_launch(void* const* d_in, const int* in_sizes, int n_in,
                              void* d_out, int out_size, void* d_ws, size_t ws_size,
                              hipStream_t stream) {
  const float* x    = (const float*)d_in[0];
  const float* h0   = (const float*)d_in[1];
  const float* c0   = (const float*)d_in[2];
  const float* W1   = (const float*)d_in[3];
  const float* U1   = (const float*)d_in[4];
  const float* b1   = (const float*)d_in[5];
  const float* W2   = (const float*)d_in[6];
  const float* U2   = (const float*)d_in[7];
  const float* b2   = (const float*)d_in[8];
  const float* fc1w = (const float*)d_in[9];
  const float* fc1b = (const float*)d_in[10];
  const float* fc2w = (const float*)d_in[11];
  const float* fc2b = (const float*)d_in[12];
  const float* fc3w = (const float*)d_in[13];
  const float* fc3b = (const float*)d_in[14];
  const float* fc4w = (const float*)d_in[15];
  const float* fc4b = (const float*)d_in[16];
  float* out = (float*)d_out;

  char* p = (char*)d_ws;
  auto alloc = [&](size_t bytes) { char* r = p; p += (bytes + 255) & ~(size_t)255; return r; };
  _Float16* xh    = (_Float16*)alloc(8388608ull * 2);        // x tiled f16 [t][dg][b][8]
  _Float16* wu1f  = (_Float16*)alloc(1536ull * 4096 * 2);    // [W1;U1] B-fragments, permuted cols
  _Float16* wu2f  = (_Float16*)alloc(2048ull * 4096 * 2);    // [W2;U2]
  _Float16* fc1wf = (_Float16*)alloc(1024ull * 512 * 2);     // fc1_w B-fragments
  float* b1p      = (float*)alloc(4096 * 4);
  float* b2p      = (float*)alloc(4096 * 4);
  _Float16* ys1   = (_Float16*)alloc(257ull * 65536 * 2);    // h1 slots, tiled: [0]=h0, [t+1]=h1_t
  _Float16* ys2   = (_Float16*)alloc(257ull * 65536 * 2);    // h2 slots, tiled
  float* cfin     = (float*)alloc(65536 * 4);                // c1 final [b][h] fp32
  _Float16* xg    = (_Float16*)alloc(256ull * 65536 * 4 * 2);// 128 MB: x-part gates
  float* part     = (float*)alloc(256ull * 64 * 36 * 4);     // FC2 partials
  int* bar        = (int*)alloc(16384 * 4);                  // 2 layers x 16KB padded flag region
  float* z2g      = (float*)alloc(2304 * 4);                 // FC2 reduced
  float* Y1       = (float*)xg;                              // FC1 out aliases xg (dead by then)
  (void)in_sizes; (void)n_in; (void)out_size; (void)ws_size;

  prep_x_kernel<<<8388608 / 256, 256, 0, stream>>>(x, xh);
  swizzle_b_kernel<<<(256 * 48 * 64) / 256, 256, 0, stream>>>(W1, U1, 512, 1536, 4096, 4096, 1, wu1f);
  swizzle_b_kernel<<<(256 * 64 * 64) / 256, 256, 0, stream>>>(W2, U2, 1024, 2048, 4096, 4096, 1, wu2f);
  swizzle_b_kernel<<<(32 * 32 * 64) / 256, 256, 0, stream>>>(fc1w, fc1w, 1024, 1024, 512, 512, 0, fc1wf);
  prep_small_kernel<<<256, 256, 0, stream>>>(b1, b2, h0, b1p, b2p, ys1, bar);
  sentinel_fill_kernel<<<8192, 256, 0, stream>>>(ys1, ys2);  // slots 1..256 := 0x7FFF sentinel

  // Layer 1: xg1 = x@W1+b1, then recurrence (h slot0 = h0; c: c0 -> cfin)
  xg_gemm_kernel<<<512, 256, 0, stream>>>(xh, (size_t)32768, 16, wu1f, b1p, xg);
  lstm_layer_kernel<<<256, NT, 0, stream>>>(xg, ys1, ys1, wu1f, 16, c0, cfin, bar);
  // Layer 2: xg2 = ys1@W2+b2 (ys1 fully materialized), then recurrence
  xg_gemm_kernel<<<512, 256, 0, stream>>>(ys1 + 65536, (size_t)65536, 32, wu2f, b2p, xg);
  lstm_layer_kernel<<<256, NT, 0, stream>>>(xg, ys2, ys1 + (size_t)256 * 65536, wu2f, 32,
                                            cfin, nullptr, bar + 8192);

  fc1_gemm_kernel<<<2048, 256, 0, stream>>>(ys2, fc1wf, fc1b, Y1);
  fc2_partial_kernel<<<256, 256, 0, stream>>>(Y1, fc2w, part);
  fc2_reduce_kernel<<<9, 256, 0, stream>>>(part, fc2b, z2g);
  fc_final_kernel<<<1, 384, 0, stream>>>(z2g, fc3w, fc3b, fc4w, fc4b, out);
}